// Round 3
// baseline (2441.494 us; speedup 1.0000x reference)
//
#include <hip/hip_runtime.h>

#define BN_S 0.9999950000374997f

typedef unsigned short ushort_t;
typedef __attribute__((ext_vector_type(8))) short bf16x8;
typedef __attribute__((ext_vector_type(8))) unsigned short u16x8;
typedef __attribute__((ext_vector_type(4))) float f32x4;

__device__ inline unsigned short f2bf(float f) {
    union { float f; unsigned u; } v; v.f = f;
    return (unsigned short)((v.u + 0x7FFFu + ((v.u >> 16) & 1u)) >> 16);
}
__device__ inline float bf2f(unsigned short h) {
    union { float f; unsigned u; } v; v.u = ((unsigned)h) << 16;
    return v.f;
}

// ---------------- gates: top-k mask + masked softmax -> p[14][32][8] ----------
__global__ void gates_k(const float* __restrict__ g, const int* __restrict__ topp,
                        float* __restrict__ p)
{
    int t = blockIdx.x * blockDim.x + threadIdx.x;
    if (t >= 14 * 32) return;
    int top = topp[0];
    float v[8]; bool sel[8];
    for (int o = 0; o < 8; ++o) { v[o] = g[t * 8 + o]; sel[o] = false; }
    for (int it = 0; it < top; ++it) {
        int bi = 0; float bv = -3.4e38f;
        for (int o = 0; o < 8; ++o)
            if (!sel[o] && v[o] > bv) { bv = v[o]; bi = o; }
        sel[bi] = true;
    }
    float mx = -3.4e38f;
    for (int o = 0; o < 8; ++o) if (sel[o]) mx = fmaxf(mx, v[o]);
    float e[8]; float sum = 0.0f;
    for (int o = 0; o < 8; ++o) { e[o] = sel[o] ? expf(v[o] - mx) : 0.0f; sum += e[o]; }
    for (int o = 0; o < 8; ++o) p[t * 8 + o] = e[o] / sum;
}

// ---------------- weight prep: f32 -> bf16 flat convert ----------------------
struct CvtArgs { const float* s[8]; ushort_t* d[8]; int n[8]; };
__global__ void cvt_k(CvtArgs a) {
    int j = blockIdx.y;
    int i = blockIdx.x * 256 + threadIdx.x;
    if (i < a.n[j]) a.d[j][i] = f2bf(a.s[j][i]);
}

// dw weights: [14][128][taps] f32 -> [14][taps][128] bf16
struct DwtArgs { const float* s[6]; ushort_t* d[6]; int t[6]; };
__global__ void dwt_k(DwtArgs a) {
    int j = blockIdx.y, m = blockIdx.x;
    int t = a.t[j];
    const float* s = a.s[j] + (long)m * 128 * t;
    ushort_t* d = a.d[j] + (long)m * t * 128;
    for (int i = threadIdx.x; i < t * 128; i += 256) {
        int tap = i >> 7, c = i & 127;
        d[i] = f2bf(s[c * t + tap]);
    }
}

// ---------------- MFMA helper: 128co x 64n tile, K=128, NHWC bf16 ------------
__device__ inline void gemm128(const ushort_t* __restrict__ w,
                               const ushort_t* __restrict__ xb,
                               int co0, int n0, int quad, int l16,
                               f32x4 acc[2][4])
{
#pragma unroll
    for (int ks = 0; ks < 4; ++ks) {
        const ushort_t* wr = w + (long)(co0 + l16) * 128 + ks * 32 + quad * 8;
        bf16x8 a0 = *(const bf16x8*)wr;
        bf16x8 a1 = *(const bf16x8*)(wr + 16 * 128);
#pragma unroll
        for (int nt = 0; nt < 4; ++nt) {
            bf16x8 bv = *(const bf16x8*)&xb[(long)(n0 + nt * 16 + l16) * 128 + ks * 32 + quad * 8];
            acc[0][nt] = __builtin_amdgcn_mfma_f32_16x16x32_bf16(a0, bv, acc[0][nt], 0, 0, 0);
            acc[1][nt] = __builtin_amdgcn_mfma_f32_16x16x32_bf16(a1, bv, acc[1][nt], 0, 0, 0);
        }
    }
}

// ---------------- preprocess: relu + 1x1 conv K=512, NCHW f32 -> NHWC bf16 ---
__global__ void __launch_bounds__(256)
preproc_k(const float* __restrict__ x, const ushort_t* __restrict__ wb,
          ushort_t* __restrict__ st)
{
    const int b = blockIdx.y, n0 = blockIdx.x * 64;
    __shared__ ushort_t lds[64 * 40];
    const int tid = threadIdx.x;
    const int wv = tid >> 6, lane = tid & 63, quad = lane >> 4, l16 = lane & 15;
    const int sn = tid & 63, k8 = tid >> 6;
    const float* xb = x + (long)b * 524288 + n0 + sn;
    f32x4 z = {0.f, 0.f, 0.f, 0.f};
    f32x4 acc[2][4];
#pragma unroll
    for (int i = 0; i < 2; ++i)
#pragma unroll
        for (int j = 0; j < 4; ++j) acc[i][j] = z;

    for (int k0 = 0; k0 < 512; k0 += 32) {
        u16x8 pk;
#pragma unroll
        for (int j = 0; j < 8; ++j) {
            float v = xb[(long)(k0 + k8 * 8 + j) * 1024];
            pk[j] = f2bf(fmaxf(v, 0.0f));
        }
        __syncthreads();
        *(u16x8*)&lds[sn * 40 + k8 * 8] = pk;
        __syncthreads();
        const ushort_t* wr = wb + (long)(wv * 32 + l16) * 512 + k0 + quad * 8;
        bf16x8 a0 = *(const bf16x8*)wr;
        bf16x8 a1 = *(const bf16x8*)(wr + 16 * 512);
#pragma unroll
        for (int nt = 0; nt < 4; ++nt) {
            bf16x8 bv = *(const bf16x8*)&lds[(nt * 16 + l16) * 40 + quad * 8];
            acc[0][nt] = __builtin_amdgcn_mfma_f32_16x16x32_bf16(a0, bv, acc[0][nt], 0, 0, 0);
            acc[1][nt] = __builtin_amdgcn_mfma_f32_16x16x32_bf16(a1, bv, acc[1][nt], 0, 0, 0);
        }
    }
    ushort_t* sb = st + (long)b * 131072;
#pragma unroll
    for (int mt = 0; mt < 2; ++mt)
#pragma unroll
        for (int nt = 0; nt < 4; ++nt) {
            int c = wv * 32 + mt * 16 + quad * 4;
            int n = n0 + nt * 16 + l16;
            ushort4 o;
            o.x = f2bf(acc[mt][nt][0] * BN_S);
            o.y = f2bf(acc[mt][nt][1] * BN_S);
            o.z = f2bf(acc[mt][nt][2] * BN_S);
            o.w = f2bf(acc[mt][nt][3] * BN_S);
            *(ushort4*)&sb[(long)n * 128 + c] = o;
        }
}

// ---------------- batched depthwise conv (relu on input), NHWC bf16 ----------
struct DwArgs {
    const ushort_t* in0; const ushort_t* in1;
    ushort_t* out0; ushort_t* out1;
    const ushort_t* wt0; const ushort_t* wt1;   // [tap][128] bf16
    int ksz0, ksz1, dil0, dil1, pad0, pad1, g0, g1;
    const float* p;   // p + m*256
};
__global__ void __launch_bounds__(256)
dw_k(DwArgs a)
{
    const int op = blockIdx.y, b = blockIdx.z, row = blockIdx.x;
    const int gi = op ? a.g1 : a.g0;
    if (a.p[b * 8 + gi] == 0.0f) return;
    const ushort_t* in = op ? a.in1 : a.in0;
    ushort_t* out = op ? a.out1 : a.out0;
    const ushort_t* wt = op ? a.wt1 : a.wt0;
    const int ksz = op ? a.ksz1 : a.ksz0;
    const int dil = op ? a.dil1 : a.dil0;
    const int pad = op ? a.pad1 : a.pad0;

    const int cg = threadIdx.x & 15;        // 8-channel group
    const int x0 = (threadIdx.x >> 4) * 2;  // 2 pixels per thread
    const ushort_t* ib = in + (long)b * 131072;
    float acc0[8], acc1[8];
#pragma unroll
    for (int j = 0; j < 8; ++j) { acc0[j] = 0.f; acc1[j] = 0.f; }

    const int nt = ksz * ksz;
    for (int t = 0; t < nt; ++t) {
        int dy = (t / ksz) * dil - pad;
        int dx = (t % ksz) * dil - pad;
        int y = row + dy;
        if ((unsigned)y >= 32u) continue;
        u16x8 wv8 = *(const u16x8*)&wt[t * 128 + cg * 8];
        int x = x0 + dx;
        if ((unsigned)x < 32u) {
            u16x8 iv = *(const u16x8*)&ib[(long)(y * 32 + x) * 128 + cg * 8];
#pragma unroll
            for (int j = 0; j < 8; ++j)
                acc0[j] += bf2f(wv8[j]) * fmaxf(bf2f(iv[j]), 0.0f);
        }
        x = x0 + 1 + dx;
        if ((unsigned)x < 32u) {
            u16x8 iv = *(const u16x8*)&ib[(long)(y * 32 + x) * 128 + cg * 8];
#pragma unroll
            for (int j = 0; j < 8; ++j)
                acc1[j] += bf2f(wv8[j]) * fmaxf(bf2f(iv[j]), 0.0f);
        }
    }
    ushort_t* ob = out + (long)b * 131072;
    u16x8 o0, o1;
#pragma unroll
    for (int j = 0; j < 8; ++j) { o0[j] = f2bf(acc0[j]); o1[j] = f2bf(acc1[j]); }
    *(u16x8*)&ob[(long)(row * 32 + x0) * 128 + cg * 8] = o0;
    *(u16x8*)&ob[(long)(row * 32 + x0 + 1) * 128 + cg * 8] = o1;
}

// ---------------- pw1: gated 1x1 conv K=128, bf16 NHWC -> bf16 NHWC ----------
struct Pw1Args {
    const ushort_t* in0; const ushort_t* in1;
    ushort_t* out0; ushort_t* out1;
    const ushort_t* w0; const ushort_t* w1;
    int gi0, gi1;
    const float* p;   // p + m*256
};
__global__ void __launch_bounds__(256)
pw1_k(Pw1Args a)
{
    const int op = blockIdx.y, b = blockIdx.z, n0 = blockIdx.x * 64;
    const int gi = op ? a.gi1 : a.gi0;
    if (a.p[b * 8 + gi] == 0.0f) return;
    const ushort_t* in = op ? a.in1 : a.in0;
    const ushort_t* w = op ? a.w1 : a.w0;
    ushort_t* out = op ? a.out1 : a.out0;
    const int tid = threadIdx.x;
    const int wv = tid >> 6, lane = tid & 63, quad = lane >> 4, l16 = lane & 15;
    f32x4 z = {0.f, 0.f, 0.f, 0.f};
    f32x4 acc[2][4];
#pragma unroll
    for (int i = 0; i < 2; ++i)
#pragma unroll
        for (int j = 0; j < 4; ++j) acc[i][j] = z;
    gemm128(w, in + (long)b * 131072, wv * 32, n0, quad, l16, acc);
    ushort_t* ob = out + (long)b * 131072;
#pragma unroll
    for (int mt = 0; mt < 2; ++mt)
#pragma unroll
        for (int nt = 0; nt < 4; ++nt) {
            int c = wv * 32 + mt * 16 + quad * 4;
            int n = n0 + nt * 16 + l16;
            ushort4 o;
            o.x = f2bf(acc[mt][nt][0] * BN_S);
            o.y = f2bf(acc[mt][nt][1] * BN_S);
            o.z = f2bf(acc[mt][nt][2] * BN_S);
            o.w = f2bf(acc[mt][nt][3] * BN_S);
            *(ushort4*)&ob[(long)n * 128 + c] = o;
        }
}

// ---------------- ACC: fused gated GEMM(s) (+pool/skip) -> RMW NCHW f32 out --
struct AccArgs {
    const ushort_t* t0; const ushort_t* t1;
    const ushort_t* w0; const ushort_t* w1;
    int g0, g1, ng;
    const ushort_t* xj;     // state bf16 NHWC, for pool/skip
    const float* p;         // p + m*256
    float* out;             // d_out
    int cofs;               // channel offset (step*128)
    ushort_t* stb;          // bf16 NHWC state out (WST only)
};
template<bool POOL, bool INIT, bool WST>
__global__ void __launch_bounds__(256)
acc_k(AccArgs a)
{
    const int b = blockIdx.y, n0 = blockIdx.x * 64;
    const int tid = threadIdx.x;
    const int wv = tid >> 6, lane = tid & 63, quad = lane >> 4, l16 = lane & 15;
    const float* pb = a.p + b * 8;
    const float ga = pb[a.g0];
    const float gb = (a.ng == 2) ? pb[a.g1] : 0.0f;
    float pw1 = 0.f, pw2 = 0.f, pw3 = 0.f;
    if (POOL) { pw1 = pb[1]; pw2 = pb[2]; pw3 = pb[3]; }
    const bool anyp = POOL && (pw1 != 0.f || pw2 != 0.f || pw3 != 0.f);
    const bool any = (ga != 0.f) || (gb != 0.f) || anyp;
    if (!INIT && !WST && !any) return;

    f32x4 z = {0.f, 0.f, 0.f, 0.f};
    f32x4 res[2][4];
#pragma unroll
    for (int i = 0; i < 2; ++i)
#pragma unroll
        for (int j = 0; j < 4; ++j) res[i][j] = z;

    if (ga != 0.f) {
        f32x4 acc[2][4];
#pragma unroll
        for (int i = 0; i < 2; ++i)
#pragma unroll
            for (int j = 0; j < 4; ++j) acc[i][j] = z;
        gemm128(a.w0, a.t0 + (long)b * 131072, wv * 32, n0, quad, l16, acc);
        float s = BN_S * ga;
#pragma unroll
        for (int i = 0; i < 2; ++i)
#pragma unroll
            for (int j = 0; j < 4; ++j) res[i][j] += acc[i][j] * s;
    }
    if (gb != 0.f) {
        f32x4 acc[2][4];
#pragma unroll
        for (int i = 0; i < 2; ++i)
#pragma unroll
            for (int j = 0; j < 4; ++j) acc[i][j] = z;
        gemm128(a.w1, a.t1 + (long)b * 131072, wv * 32, n0, quad, l16, acc);
        float s = BN_S * gb;
#pragma unroll
        for (int i = 0; i < 2; ++i)
#pragma unroll
            for (int j = 0; j < 4; ++j) res[i][j] += acc[i][j] * s;
    }

    if constexpr (POOL) {
        if (anyp) {
            __shared__ ushort_t xl[128 * 136];
            const int r0 = n0 >> 5;   // first image row of this block
            const ushort_t* xb = a.xj + (long)b * 131072;
#pragma unroll
            for (int i = 0; i < 8; ++i) {
                int idx = i * 256 + tid;
                int cg = idx & 15, pxl = idx >> 4;     // pxl 0..127
                int rl = pxl >> 5, xx = pxl & 31;
                int gy = r0 - 1 + rl;
                u16x8 v;
                if ((unsigned)gy < 32u)
                    v = *(const u16x8*)&xb[(long)(gy * 32 + xx) * 128 + cg * 8];
                else
#pragma unroll
                    for (int j = 0; j < 8; ++j) v[j] = 0;
                *(u16x8*)&xl[pxl * 136 + cg * 8] = v;
            }
            __syncthreads();
            float s1 = pw1 * BN_S, s2 = pw2 * BN_S;
#pragma unroll
            for (int mt = 0; mt < 2; ++mt)
#pragma unroll
                for (int nt = 0; nt < 4; ++nt) {
                    int nl = nt * 16 + l16;
                    int xx = nl & 31, rr = nl >> 5;  // local row 0/1
                    int gy = r0 + rr;
                    int y0 = max(gy - 1, 0), y1 = min(gy + 1, 31);
                    int xa = max(xx - 1, 0), xb2 = min(xx + 1, 31);
                    float cnt = (float)((y1 - y0 + 1) * (xb2 - xa + 1));
#pragma unroll
                    for (int r = 0; r < 4; ++r) {
                        int c = wv * 32 + mt * 16 + quad * 4 + r;
                        float mx = -3.4e38f, sm = 0.f;
                        for (int yy = y0; yy <= y1; ++yy) {
                            int pl = (yy - (r0 - 1)) * 32;
                            for (int x2 = xa; x2 <= xb2; ++x2) {
                                float v = bf2f(xl[(pl + x2) * 136 + c]);
                                mx = fmaxf(mx, v); sm += v;
                            }
                        }
                        float ctr = bf2f(xl[((1 + rr) * 32 + xx) * 136 + c]);
                        res[mt][nt][r] += s1 * mx + s2 * (sm / cnt) + pw3 * ctr;
                    }
                }
        }
    }

    float* ob = a.out + (long)b * 524288 + (long)a.cofs * 1024;
    ushort_t* sb = WST ? (a.stb + (long)b * 131072) : (ushort_t*)0;
#pragma unroll
    for (int mt = 0; mt < 2; ++mt)
#pragma unroll
        for (int nt = 0; nt < 4; ++nt) {
            int c0 = wv * 32 + mt * 16 + quad * 4;
            int n = n0 + nt * 16 + l16;
            float v[4];
#pragma unroll
            for (int r = 0; r < 4; ++r) {
                v[r] = res[mt][nt][r];
                if (!INIT) v[r] += ob[(long)(c0 + r) * 1024 + n];
            }
            if (INIT || any) {
#pragma unroll
                for (int r = 0; r < 4; ++r)
                    ob[(long)(c0 + r) * 1024 + n] = v[r];
            }
            if (WST) {
                ushort4 o;
                o.x = f2bf(v[0]); o.y = f2bf(v[1]);
                o.z = f2bf(v[2]); o.w = f2bf(v[3]);
                *(ushort4*)&sb[(long)n * 128 + c0] = o;
            }
        }
}

// =============================================================================
extern "C" void kernel_launch(void* const* d_in, const int* in_sizes, int n_in,
                              void* d_out, int out_size, void* d_ws, size_t ws_size,
                              hipStream_t stream)
{
    const float* s0   = (const float*)d_in[0];
    const float* s1   = (const float*)d_in[1];
    const float* gts  = (const float*)d_in[2];
    const float* pre0 = (const float*)d_in[3];
    const float* pre1 = (const float*)d_in[4];
    const float* s3d1 = (const float*)d_in[5];
    const float* s3p1 = (const float*)d_in[6];
    const float* s3d2 = (const float*)d_in[7];
    const float* s3p2 = (const float*)d_in[8];
    const float* s5d1 = (const float*)d_in[9];
    const float* s5p1 = (const float*)d_in[10];
    const float* s5d2 = (const float*)d_in[11];
    const float* s5p2 = (const float*)d_in[12];
    const float* d3d  = (const float*)d_in[13];
    const float* d3p  = (const float*)d_in[14];
    const float* d5d  = (const float*)d_in[15];
    const float* d5p  = (const float*)d_in[16];
    const int*   topp = (const int*)d_in[17];

    // ---- workspace layout: total 62,119,936 B (< 64 MiB; round-1's 67.1 MB
    // was proven safe, round-2's 78.9 MB overflowed and corrupted harness
    // buffers -> post-timing divergence) ----
    char* w = (char*)d_ws;
    float* p = (float*)w;                w += 16384;
    ushort_t* pre0b = (ushort_t*)w;      w += 131072;
    ushort_t* pre1b = (ushort_t*)w;      w += 131072;
    ushort_t* s3p1b = (ushort_t*)w;      w += 458752;
    ushort_t* s3p2b = (ushort_t*)w;      w += 458752;
    ushort_t* s5p1b = (ushort_t*)w;      w += 458752;
    ushort_t* s5p2b = (ushort_t*)w;      w += 458752;
    ushort_t* d3pb  = (ushort_t*)w;      w += 458752;
    ushort_t* d5pb  = (ushort_t*)w;      w += 458752;
    ushort_t* s3d1t = (ushort_t*)w;      w += 32768;
    ushort_t* s3d2t = (ushort_t*)w;      w += 32768;
    ushort_t* d3dt  = (ushort_t*)w;      w += 32768;
    ushort_t* s5d1t = (ushort_t*)w;      w += 90112;
    ushort_t* s5d2t = (ushort_t*)w;      w += 90112;
    ushort_t* d5dt  = (ushort_t*)w;      w += 90112;
    ushort_t* stb[5];
    for (int i = 0; i < 5; ++i) { stb[i] = (ushort_t*)w; w += 8388608; }
    ushort_t* t0 = (ushort_t*)w;         w += 8388608;
    ushort_t* t1 = (ushort_t*)w;         w += 8388608;

    // ---- prep: weight conversions ----
    CvtArgs ca;
    ca.s[0] = pre0; ca.d[0] = pre0b; ca.n[0] = 65536;
    ca.s[1] = pre1; ca.d[1] = pre1b; ca.n[1] = 65536;
    ca.s[2] = s3p1; ca.d[2] = s3p1b; ca.n[2] = 229376;
    ca.s[3] = s3p2; ca.d[3] = s3p2b; ca.n[3] = 229376;
    ca.s[4] = s5p1; ca.d[4] = s5p1b; ca.n[4] = 229376;
    ca.s[5] = s5p2; ca.d[5] = s5p2b; ca.n[5] = 229376;
    ca.s[6] = d3p;  ca.d[6] = d3pb;  ca.n[6] = 229376;
    ca.s[7] = d5p;  ca.d[7] = d5pb;  ca.n[7] = 229376;
    cvt_k<<<dim3(896, 8), 256, 0, stream>>>(ca);

    DwtArgs da;
    da.s[0] = s3d1; da.d[0] = s3d1t; da.t[0] = 9;
    da.s[1] = s3d2; da.d[1] = s3d2t; da.t[1] = 9;
    da.s[2] = d3d;  da.d[2] = d3dt;  da.t[2] = 9;
    da.s[3] = s5d1; da.d[3] = s5d1t; da.t[3] = 25;
    da.s[4] = s5d2; da.d[4] = s5d2t; da.t[4] = 25;
    da.s[5] = d5d;  da.d[5] = d5dt;  da.t[5] = 25;
    dwt_k<<<dim3(14, 6), 256, 0, stream>>>(da);

    gates_k<<<2, 256, 0, stream>>>(gts, topp, p);

    preproc_k<<<dim3(16, 32), 256, 0, stream>>>(s0, pre0b, stb[0]);
    preproc_k<<<dim3(16, 32), 256, 0, stream>>>(s1, pre1b, stb[1]);

    const dim3 dwg1(32, 1, 32), pwg1(16, 1, 32), dwg2(32, 2, 32), acg(16, 32);
    int offset = 0;
    for (int i = 0; i < 4; ++i) {
        const int cnt = 2 + i;
        for (int j = 0; j < cnt; ++j) {
            const int m = offset + j;
            const float* pm = p + (long)m * 256;
            const ushort_t* xj = stb[j];

            // ---- sep_conv_3x3 (gate 4): xj -> t0 -> t1 -> t0 -> out ----
            DwArgs d31 = { xj, xj, t0, t0,
                           s3d1t + (long)m * 1152, s3d1t + (long)m * 1152,
                           3, 3, 1, 1, 1, 1, 4, 4, pm };
            dw_k<<<dwg1, 256, 0, stream>>>(d31);
            Pw1Args p31 = { t0, t0, t1, t1,
                            s3p1b + (long)m * 16384, s3p1b + (long)m * 16384,
                            4, 4, pm };
            pw1_k<<<pwg1, 256, 0, stream>>>(p31);
            DwArgs d32 = { t1, t1, t0, t0,
                           s3d2t + (long)m * 1152, s3d2t + (long)m * 1152,
                           3, 3, 1, 1, 1, 1, 4, 4, pm };
            dw_k<<<dwg1, 256, 0, stream>>>(d32);
            AccArgs a3 = { t0, t0,
                           s3p2b + (long)m * 16384, s3p2b + (long)m * 16384,
                           4, 4, 1, xj, pm, (float*)d_out, i * 128, (ushort_t*)0 };
            if (j == 0) acc_k<true, true, false><<<acg, 256, 0, stream>>>(a3);
            else        acc_k<true, false, false><<<acg, 256, 0, stream>>>(a3);

            // ---- sep_conv_5x5 (gate 5): xj -> t0 -> t1 -> t0 -> out ----
            DwArgs d51 = { xj, xj, t0, t0,
                           s5d1t + (long)m * 3200, s5d1t + (long)m * 3200,
                           5, 5, 1, 1, 2, 2, 5, 5, pm };
            dw_k<<<dwg1, 256, 0, stream>>>(d51);
            Pw1Args p51 = { t0, t0, t1, t1,
                            s5p1b + (long)m * 16384, s5p1b + (long)m * 16384,
                            5, 5, pm };
            pw1_k<<<pwg1, 256, 0, stream>>>(p51);
            DwArgs d52 = { t1, t1, t0, t0,
                           s5d2t + (long)m * 3200, s5d2t + (long)m * 3200,
                           5, 5, 1, 1, 2, 2, 5, 5, pm };
            dw_k<<<dwg1, 256, 0, stream>>>(d52);
            AccArgs a5 = { t0, t0,
                           s5p2b + (long)m * 16384, s5p2b + (long)m * 16384,
                           5, 5, 1, (const ushort_t*)0, pm, (float*)d_out, i * 128,
                           (ushort_t*)0 };
            acc_k<false, false, false><<<acg, 256, 0, stream>>>(a5);

            // ---- dil_conv_3x3 + dil_conv_5x5 (gates 6,7): pair ----
            DwArgs dd = { xj, xj, t0, t1,
                          d3dt + (long)m * 1152, d5dt + (long)m * 3200,
                          3, 5, 2, 2, 2, 4, 6, 7, pm };
            dw_k<<<dwg2, 256, 0, stream>>>(dd);
            bool wst = (j == cnt - 1) && (i < 3);
            AccArgs ad = { t0, t1,
                           d3pb + (long)m * 16384, d5pb + (long)m * 16384,
                           6, 7, 2, (const ushort_t*)0, pm, (float*)d_out, i * 128,
                           wst ? stb[2 + i] : (ushort_t*)0 };
            if (wst) acc_k<false, false, true><<<acg, 256, 0, stream>>>(ad);
            else     acc_k<false, false, false><<<acg, 256, 0, stream>>>(ad);
        }
        offset += cnt;
    }
}